// Round 1
// 256.074 us; speedup vs baseline: 1.0496x; 1.0496x over previous
//
#include <hip/hip_runtime.h>

#define SEQ 4096
#define DM 1024
#define DS 64
#define KS 64

#define TCH 64            // channels per block
#define TT  64            // t outputs per block
#define R   8             // outputs per thread
#define NROW (TT + 64)    // 128 staged rows: t in [t0-32, t0+95]

// ---------------------------------------------------------------------------
// async global->LDS helper (16B per lane; LDS dest = wave-uniform base + lane*16)
// ---------------------------------------------------------------------------
typedef const __attribute__((address_space(1))) void* gas_ptr;
typedef __attribute__((address_space(3))) void* las_ptr;
__device__ __forceinline__ void async_cp16(const void* g, void* s) {
    __builtin_amdgcn_global_load_lds((gas_ptr)g, (las_ptr)s, 16, 0, 0);
}

// ---------------------------------------------------------------------------
// Kernel 1: csum[d] = sum_m C[m, d]
// ---------------------------------------------------------------------------
__global__ void csum_kernel(const float* __restrict__ C, float* __restrict__ csum) {
    int d    = threadIdx.x & 63;
    int mloc = threadIdx.x >> 6;
    int m0   = blockIdx.x * 64;
    float s = 0.f;
#pragma unroll
    for (int j = 0; j < 16; ++j)
        s += C[(m0 + j * 4 + mloc) * DS + d];
    __shared__ float red[4][64];
    red[mloc][d] = s;
    __syncthreads();
    if (threadIdx.x < 64) {
        float t = red[0][d] + red[1][d] + red[2][d] + red[3][d];
        atomicAdd(&csum[d], t);
    }
}

// ---------------------------------------------------------------------------
// Kernel 2: Ktl[l*DM + k] = sum_d csum[d] * exp(A[d]*dt[k]*l) * B[d, k]
// ---------------------------------------------------------------------------
__global__ void taps_kernel(const float* __restrict__ A, const float* __restrict__ B,
                            const float* __restrict__ log_dt,
                            const float* __restrict__ csum, float* __restrict__ Ktl) {
    int g = blockIdx.x * blockDim.x + threadIdx.x;
    int k = g & (DM - 1);
    int l = g >> 10;
    float dt = __expf(log_dt[k]);
    float fl = (float)l;
    float acc = 0.f;
#pragma unroll 8
    for (int d = 0; d < DS; ++d)
        acc += csum[d] * __expf(A[d] * dt * fl) * B[d * DM + k];
    Ktl[g] = acc;
}

// ---------------------------------------------------------------------------
// Main conv. LDS-staged u tile + taps; circular register window, full unroll.
// y[b,t,k] = D[k]*u[b,t,k] + sum_l Kt[l,k]*u[b,t+31-l,k]
// row(t) in tile = t - (t0-32); for output r of group tg: row = tg*R + r + 63 - l
// ---------------------------------------------------------------------------
__global__ __launch_bounds__(256, 3)
void conv_kernel(const float* __restrict__ u, const float* __restrict__ Ktl,
                 const float* __restrict__ D, float* __restrict__ y) {
    __shared__ __align__(16) float smem_u[NROW * TCH];   // 32 KB, row stride 256B
    __shared__ __align__(16) float smem_t[KS * TCH];     // 16 KB, row stride 256B

    int k0 = blockIdx.x * TCH;
    int t0 = blockIdx.y * TT;
    int b  = blockIdx.z;

    int lane = threadIdx.x & 63;
    int wv   = threadIdx.x >> 6;

    const float* gt = u + (size_t)b * SEQ * DM + (size_t)(t0 - 32) * DM + k0; // tile origin (row 0 = t0-32)

    bool interior = (blockIdx.y > 0) && (blockIdx.y + 1 < SEQ / TT);

    // ---- stage taps: 16 KB = 4 iters x 4KB ----
#pragma unroll
    for (int j = 0; j < 4; ++j) {
        int fb = j * 4096 + wv * 1024;          // wave-uniform byte offset
        int f  = fb + lane * 16;
        int l  = f >> 8;
        int c  = (f & 255) >> 2;
        async_cp16(Ktl + l * DM + k0 + c, (char*)smem_t + fb);
    }

    // ---- stage u tile: 32 KB = 8 iters x 4KB ----
    if (interior) {
#pragma unroll
        for (int j = 0; j < 8; ++j) {
            int fb = j * 4096 + wv * 1024;
            int f  = fb + lane * 16;
            int r  = f >> 8;
            int c  = (f & 255) >> 2;
            async_cp16(gt + (size_t)r * DM + c, (char*)smem_u + fb);
        }
    } else {
        // guarded VGPR path, zero-fill OOB rows
#pragma unroll
        for (int j = 0; j < 8; ++j) {
            int f = j * 4096 + threadIdx.x * 16;
            int r = f >> 8;
            int c = (f & 255) >> 2;
            int t = t0 - 32 + r;
            float4 v = make_float4(0.f, 0.f, 0.f, 0.f);
            if (t >= 0 && t < SEQ)
                v = *(const float4*)(gt + (size_t)r * DM + c);
            *(float4*)((char*)smem_u + f) = v;
        }
    }
    __syncthreads();

    // ---- compute: circular 16-slot window over tile rows ----
    int c2 = threadIdx.x & 31;          // channel-pair lane
    int tg = threadIdx.x >> 5;          // t-group 0..7
    int ts = t0 + tg * R;
    int rb = tg * R;                    // row(ts + r + 31 - l) = rb + r + 63 - l

    const float2* us = (const float2*)smem_u;   // [row][32]
    const float2* tp = (const float2*)smem_t;   // [l][32]

    float2 acc[R];
#pragma unroll
    for (int r = 0; r < R; ++r) acc[r] = make_float2(0.f, 0.f);

    float2 D2 = *(const float2*)(D + k0 + 2 * c2);

    // init window: rows m = 55..70 (m relative to rb); slot = m & 15
    float2 w[16];
#pragma unroll
    for (int m = 55; m <= 70; ++m)
        w[m & 15] = us[(rb + m) * 32 + c2];

#pragma unroll
    for (int l = 0; l < 64; ++l) {
        float2 t2 = tp[l * 32 + c2];
#pragma unroll
        for (int r = 0; r < R; ++r) {
            float2 uv = w[(r + 63 - l) & 15];
            acc[r].x = fmaf(t2.x, uv.x, acc[r].x);
            acc[r].y = fmaf(t2.y, uv.y, acc[r].y);
        }
        if (l == 31) {   // window slots m = r+32 hold u[ts+r]: fold in D*u
#pragma unroll
            for (int r = 0; r < R; ++r) {
                float2 uv = w[(r + 32) & 15];
                acc[r].x = fmaf(D2.x, uv.x, acc[r].x);
                acc[r].y = fmaf(D2.y, uv.y, acc[r].y);
            }
        }
        if (l <= 54) {   // prefetch row m = 54-l (first used at iter l+16)
            int m = 54 - l;
            w[m & 15] = us[(rb + m) * 32 + c2];
        }
    }

    float2* yp2 = (float2*)y + (size_t)b * SEQ * (DM / 2) + (size_t)ts * (DM / 2) + (k0 >> 1) + c2;
#pragma unroll
    for (int r = 0; r < R; ++r)
        yp2[(size_t)r * (DM / 2)] = acc[r];
}

// ---------------------------------------------------------------------------
extern "C" void kernel_launch(void* const* d_in, const int* in_sizes, int n_in,
                              void* d_out, int out_size, void* d_ws, size_t ws_size,
                              hipStream_t stream) {
    const float* u      = (const float*)d_in[0];
    const float* A      = (const float*)d_in[1];
    const float* Bp     = (const float*)d_in[2];
    const float* Cp     = (const float*)d_in[3];
    const float* Dp     = (const float*)d_in[4];
    const float* log_dt = (const float*)d_in[5];
    float* y = (float*)d_out;

    float* csum = (float*)d_ws;            // 64 floats
    float* Ktl  = csum + 64;               // 65536 floats, [l][k]

    hipMemsetAsync(csum, 0, DS * sizeof(float), stream);
    csum_kernel<<<16, 256, 0, stream>>>(Cp, csum);
    taps_kernel<<<(DM * KS) / 256, 256, 0, stream>>>(A, Bp, log_dt, csum, Ktl);

    dim3 grid(DM / TCH, SEQ / TT, 8);
    conv_kernel<<<grid, 256, 0, stream>>>(u, Ktl, Dp, y);
}